// Round 1
// baseline (358.833 us; speedup 1.0000x reference)
//
#include <hip/hip_runtime.h>
#include <stdint.h>

// KMaxPool: rows of S=4096 f32, take top-K=8 values, output in original index order.
// One wave (64 lanes) per row. Single HBM pass: row kept in VGPRs (16 x float4/lane).
#define WPB    4      // waves per block (block = 256)
#define CAP    96     // LDS candidate list capacity per row (bound is ~64 + tie slack)
#define KK     8
#define SLEN   4096
#define CHUNKS 16     // SLEN / 64 lanes / 4 (float4)

__global__ __launch_bounds__(256, 4)
void kmax_kernel(const float* __restrict__ x, float* __restrict__ out, int nrows) {
    const int wave = threadIdx.x >> 6;
    const int lane = threadIdx.x & 63;
    const int row  = blockIdx.x * WPB + wave;
    const bool active = row < nrows;

    __shared__ int   s_cnt[WPB];
    __shared__ float s_val[WPB][CAP];
    __shared__ int   s_idx[WPB][CAP];

    if (lane == 0) s_cnt[wave] = 0;
    __syncthreads();

    const float NEG_INF = __int_as_float(0xff800000);

    float Tthr = 0.0f;
    float4 f[CHUNKS];

    if (active) {
        const float4* xr = reinterpret_cast<const float4*>(x + (size_t)row * SLEN);
        // 1. load entire row into registers, coalesced 16B/lane
        #pragma unroll
        for (int j = 0; j < CHUNKS; ++j)
            f[j] = xr[j * 64 + lane];

        // 2. 8 substream running maxes per lane (8 disjoint groups of 8 values)
        float m[8];
        #pragma unroll
        for (int e = 0; e < 8; ++e) m[e] = NEG_INF;
        #pragma unroll
        for (int j = 0; j < CHUNKS; ++j) {
            const int b = (j & 1) * 4;
            m[b + 0] = fmaxf(m[b + 0], f[j].x);
            m[b + 1] = fmaxf(m[b + 1], f[j].y);
            m[b + 2] = fmaxf(m[b + 2], f[j].z);
            m[b + 3] = fmaxf(m[b + 3], f[j].w);
        }

        // sort m[0..7] descending: Batcher odd-even mergesort, 19 comparators
        #define MCAS(a, b) { float hi = fmaxf(m[a], m[b]); float lo = fminf(m[a], m[b]); m[a] = hi; m[b] = lo; }
        MCAS(0,1) MCAS(2,3) MCAS(4,5) MCAS(6,7)
        MCAS(0,2) MCAS(1,3) MCAS(4,6) MCAS(5,7)
        MCAS(1,2) MCAS(5,6)
        MCAS(0,4) MCAS(1,5) MCAS(2,6) MCAS(3,7)
        MCAS(2,4) MCAS(3,5)
        MCAS(1,2) MCAS(3,4) MCAS(5,6)
        #undef MCAS

        // 3. eight wave-max extraction rounds over sorted lane lists
        //    -> Tthr = 8th extracted value, a guaranteed lower bound on the
        //       true 8th-largest of the row.
        #pragma unroll
        for (int t = 0; t < KK; ++t) {
            float r = m[0];
            #pragma unroll
            for (int off = 32; off >= 1; off >>= 1)
                r = fmaxf(r, __shfl_xor(r, off, 64));
            const bool win = (m[0] == r);
            m[0] = win ? m[1] : m[0];
            m[1] = win ? m[2] : m[1];
            m[2] = win ? m[3] : m[2];
            m[3] = win ? m[4] : m[3];
            m[4] = win ? m[5] : m[4];
            m[5] = win ? m[6] : m[5];
            m[6] = win ? m[7] : m[6];
            m[7] = win ? NEG_INF : m[7];
            Tthr = r;
        }

        // 4. exact pass from registers: push every (val, idx) with val >= Tthr.
        //    For distinct values at most 64 elements qualify (<=8 substreams of 8).
        #pragma unroll
        for (int j = 0; j < CHUNKS; ++j) {
            const float4 v = f[j];
            const bool p0 = v.x >= Tthr, p1 = v.y >= Tthr, p2 = v.z >= Tthr, p3 = v.w >= Tthr;
            if (p0 || p1 || p2 || p3) {
                const int base = (j * 64 + lane) * 4;
                if (p0) { int p = atomicAdd(&s_cnt[wave], 1); if (p < CAP) { s_val[wave][p] = v.x; s_idx[wave][p] = base + 0; } }
                if (p1) { int p = atomicAdd(&s_cnt[wave], 1); if (p < CAP) { s_val[wave][p] = v.y; s_idx[wave][p] = base + 1; } }
                if (p2) { int p = atomicAdd(&s_cnt[wave], 1); if (p < CAP) { s_val[wave][p] = v.z; s_idx[wave][p] = base + 2; } }
                if (p3) { int p = atomicAdd(&s_cnt[wave], 1); if (p < CAP) { s_val[wave][p] = v.w; s_idx[wave][p] = base + 3; } }
            }
        }
    }

    __syncthreads();

    if (active) {
        int n = s_cnt[wave];
        if (n > CAP) n = CAP;
        // one candidate per lane (n >= 8 guaranteed: the 8 extracted substream
        // maxes are distinct elements with value >= Tthr)
        float v  = (lane < n) ? s_val[wave][lane] : NEG_INF;
        int   id = (lane < n) ? s_idx[wave][lane] : 0x7FFFFFFF;

        // 5. exact top-8 with JAX top_k tie semantics: (value desc, index asc)
        float rv[KK]; int ri[KK];
        #pragma unroll
        for (int t = 0; t < KK; ++t) {
            float av = v; int ai = id;
            #pragma unroll
            for (int off = 32; off >= 1; off >>= 1) {
                float ov = __shfl_xor(av, off, 64);
                int   oi = __shfl_xor(ai, off, 64);
                const bool take = (ov > av) || (ov == av && oi < ai);
                av = take ? ov : av;
                ai = take ? oi : ai;
            }
            rv[t] = av; ri[t] = ai;           // wave-uniform winner
            if (id == ai) v = NEG_INF;        // consume (indices are unique)
        }

        // 6. reorder the 8 winners by ascending original index (uniform sort network)
        #define ICAS(a, b) { bool sw = ri[a] > ri[b]; \
            int   tlo = sw ? ri[b] : ri[a]; int   thi = sw ? ri[a] : ri[b]; ri[a] = tlo; ri[b] = thi; \
            float vlo = sw ? rv[b] : rv[a]; float vhi = sw ? rv[a] : rv[b]; rv[a] = vlo; rv[b] = vhi; }
        ICAS(0,1) ICAS(2,3) ICAS(4,5) ICAS(6,7)
        ICAS(0,2) ICAS(1,3) ICAS(4,6) ICAS(5,7)
        ICAS(1,2) ICAS(5,6)
        ICAS(0,4) ICAS(1,5) ICAS(2,6) ICAS(3,7)
        ICAS(2,4) ICAS(3,5)
        ICAS(1,2) ICAS(3,4) ICAS(5,6)
        #undef ICAS

        if (lane == 0) {
            float4* o = reinterpret_cast<float4*>(out + (size_t)row * KK);
            o[0] = make_float4(rv[0], rv[1], rv[2], rv[3]);
            o[1] = make_float4(rv[4], rv[5], rv[6], rv[7]);
        }
    }
}

extern "C" void kernel_launch(void* const* d_in, const int* in_sizes, int n_in,
                              void* d_out, int out_size, void* d_ws, size_t ws_size,
                              hipStream_t stream) {
    const float* x = (const float*)d_in[0];
    float* out = (float*)d_out;
    const int nrows = out_size / KK;                 // 16 * 1024 = 16384
    const int blocks = (nrows + WPB - 1) / WPB;      // 4096
    kmax_kernel<<<blocks, 256, 0, stream>>>(x, out, nrows);
}